// Round 21
// baseline (447.437 us; speedup 1.0000x reference)
//
#include <hip/hip_runtime.h>
#include <float.h>

#define N_ROWS 65536
#define DIM 256
#define K_CODES 4096
#define MARGIN 0.025f

typedef __attribute__((ext_vector_type(8))) short short8;   // 8 bf16 (4 VGPR)
typedef __attribute__((ext_vector_type(4))) float f32x4;
typedef __attribute__((ext_vector_type(4))) unsigned int u32x4;

__device__ __forceinline__ unsigned short f2bf(float f) {   // RNE
    unsigned u = __float_as_uint(f);
    return (unsigned short)((u + 0x7FFFu + ((u >> 16) & 1u)) >> 16);
}
__device__ __forceinline__ float bf2f(unsigned short h) {
    return __uint_as_float((unsigned)h << 16);
}

// async global->LDS DMA, 16B per lane; LDS dest = wave-uniform base + lane*16
__device__ __forceinline__ void gload16(const void* gsrc, void* ldst) {
    __builtin_amdgcn_global_load_lds(
        (__attribute__((address_space(1))) unsigned int*)gsrc,
        (__attribute__((address_space(3))) unsigned int*)ldst,
        16, 0, 0);
}

// ===========================================================================
// k_prep: fused prep (validated r20). blockIdx ranges:
//   [0,16) emb_sqr (+flagcnt=0) | [16,1040) inp_sqr | [1040,2064) esplit
// ===========================================================================
__launch_bounds__(256)
__global__ void k_prep(const float* __restrict__ X, const float* __restrict__ E,
                       float* __restrict__ emb_sqr, float* __restrict__ S,
                       float* __restrict__ ET, unsigned short* __restrict__ EThi,
                       int* __restrict__ flagcnt) {
    const int bid = blockIdx.x;
    const int tid = threadIdx.x;

    if (bid < 16) {
        if (bid == 0 && tid == 0) *flagcnt = 0;
        int k = bid * 256 + tid;
        float e0 = E[k];
        float s = __fmul_rn(e0, e0);
        for (int d = 1; d < DIM; ++d) {
            float v = E[(size_t)d * K_CODES + k];
            s = __fadd_rn(s, __fmul_rn(v, v));
        }
        emb_sqr[k] = s;
    } else if (bid < 1040) {
        __shared__ float xs[64][261];
        const int rowBase = (bid - 16) * 64;
        const float4* Xv = (const float4*)(X + (size_t)rowBase * DIM);
#pragma unroll
        for (int it = 0; it < 16; ++it) {
            int lin = it * 256 + tid;
            int r = lin >> 6, c4 = lin & 63;
            float4 v = Xv[lin];
            xs[r][c4 * 4 + 0] = v.x; xs[r][c4 * 4 + 1] = v.y;
            xs[r][c4 * 4 + 2] = v.z; xs[r][c4 * 4 + 3] = v.w;
        }
        __syncthreads();
        if (tid < 64) {
            const float* x = xs[tid];
            float b[2];
#pragma unroll
            for (int h = 0; h < 2; ++h) {
                const float* p = x + h * 128;
                float r[8];
#pragma unroll
                for (int j = 0; j < 8; ++j) r[j] = __fmul_rn(p[j], p[j]);
                for (int i = 8; i < 128; i += 8)
#pragma unroll
                    for (int j = 0; j < 8; ++j)
                        r[j] = __fadd_rn(r[j], __fmul_rn(p[i + j], p[i + j]));
                b[h] = __fadd_rn(__fadd_rn(__fadd_rn(r[0], r[1]), __fadd_rn(r[2], r[3])),
                                 __fadd_rn(__fadd_rn(r[4], r[5]), __fadd_rn(r[6], r[7])));
            }
            S[rowBase + tid] = __fadd_rn(b[0], b[1]);
        }
    } else {
        __shared__ float t[32][33];
        const int e = bid - 1040;               // 0..1023
        const int k0 = (e & 127) * 32;
        const int d0 = (e >> 7) * 32;
        const int tx = tid & 31, ty = tid >> 5;
#pragma unroll
        for (int i = 0; i < 32; i += 8)
            t[ty + i][tx] = E[(size_t)(d0 + ty + i) * K_CODES + k0 + tx];
        __syncthreads();
#pragma unroll
        for (int i = 0; i < 32; i += 8) {
            float w = t[tx][ty + i];
            size_t o = (size_t)(k0 + ty + i) * DIM + d0 + tx;
            ET[o] = w;
            EThi[o] = f2bf(w);
        }
    }
}

// ===========================================================================
// k_filter v15: K-SPLIT. r18/r20 filter body verbatim, but each block scans
// 128 rows x 2048 codes (blockIdx.y = code half) -> grid 1024 blocks =
// 4 blocks/CU (was 2, grid-limited!). LDS 33792 x4 = 132KB fits; VGPR 64.
// Per-row (v1, idx|flag<<31) partials written to ws; k_merge finalizes.
// Flag completeness: d_c-bv<M => d_c-v_h<M (v_h>=bv) => caught by half's
// own bit; half-best caught by cross-half check in merge. Conservative.
// ===========================================================================
#define FBM 128
#define FBN 128

__launch_bounds__(512, 4)
__global__ void k_filter(const float* __restrict__ X,
                         const unsigned short* __restrict__ EThi,
                         const float* __restrict__ emb_sqr,
                         float* __restrict__ v1h, unsigned* __restrict__ i1h) {
    __shared__ __align__(16) char lds[33792];   // bufs 3x8KB; reduce aliases

    const int tid = threadIdx.x;
    const int lane = tid & 63;
    const int wid = tid >> 6;
    const int wm = wid & 3;          // row-wave: 32 rows each
    const int wn = wid >> 2;         // col-wave: 64 codes each
    const int rowBase = blockIdx.x * FBM;
    const int chalf = blockIdx.y;    // code half: [chalf*2048, +2048)
    const unsigned short* EThiH = EThi + (size_t)chalf * 2048 * DIM;
    const int l15 = lane & 15, l4 = lane >> 4;

    // ---- prologue: stage Xh slice per 32-d step, load A-frags to registers
    short8 ah[2][8];
    {
        const int prow = tid >> 2;              // 0..127
        const int pd = (tid & 3) * 8;           // 0,8,16,24
        const int wroff = prow * 128 + ((pd * 2) ^ ((prow & 7) << 4));
#pragma unroll
        for (int ks = 0; ks < 8; ++ks) {
            float4 v0 = *(const float4*)&X[(size_t)(rowBase + prow) * DIM + ks * 32 + pd];
            float4 v1 = *(const float4*)&X[(size_t)(rowBase + prow) * DIM + ks * 32 + pd + 4];
            float f[8] = {v0.x, v0.y, v0.z, v0.w, v1.x, v1.y, v1.z, v1.w};
            unsigned H[4];
#pragma unroll
            for (int p = 0; p < 4; ++p) {
                unsigned short ha = f2bf(f[2 * p]), hb = f2bf(f[2 * p + 1]);
                H[p] = (unsigned)ha | ((unsigned)hb << 16);
            }
            u32x4 Hv = {H[0], H[1], H[2], H[3]};
            *(u32x4*)(lds + wroff) = Hv;
            __syncthreads();
#pragma unroll
            for (int mf = 0; mf < 2; ++mf) {
                int rl = wm * 32 + mf * 16 + l15;
                int off = rl * 128 + ((l4 * 16) ^ ((rl & 7) << 4));
                ah[mf][ks] = *(const short8*)(lds + off);
            }
            __syncthreads();   // full drain -> clean counter slate
        }
    }

    // ---- per-(mf,r) best + packed(idx | flag<<31)
    float v1r[8];
    unsigned i1r[8];
#pragma unroll
    for (int s = 0; s < 8; ++s) { v1r[s] = FLT_MAX; i1r[s] = 0u; }

    // ---- gload_lds source geometry (rule #21 inverse swizzle, validated r8)
    const int gr = (wid << 4) + (lane >> 2);
    const int gc = (lane & 3) ^ ((lane >> 3) & 3);
    const size_t goff = (size_t)gr * DIM + gc * 8;      // u16 elements

    // ---- B-frag read offsets (swizzled), hoisted
    int boff[4];
#pragma unroll
    for (int nf = 0; nf < 4; ++nf) {
        int cl = wn * 64 + nf * 16 + l15;
        boff[nf] = cl * 64 + ((l4 ^ ((cl >> 1) & 3)) << 4);
    }

    // ---- stage slices 0 (buf0) and 1 (buf1)
    gload16(EThiH + goff, lds + (wid << 10));
    gload16(EThiH + 32 + goff, lds + 8192 + (wid << 10));
    asm volatile("s_waitcnt vmcnt(1)" ::: "memory");   // slice 0 landed
    __builtin_amdgcn_sched_barrier(0);
    __builtin_amdgcn_s_barrier();
    __builtin_amdgcn_sched_barrier(0);

    int bcur = 0;   // buffer holding slice t; rotates 0->1->2->0
    for (int ct = 0; ct < 16; ++ct) {              // 16 code tiles (half)
        f32x4 acc[2][4];
#pragma unroll
        for (int mf = 0; mf < 2; ++mf)
#pragma unroll
            for (int nf = 0; nf < 4; ++nf) acc[mf][nf] = (f32x4)0.f;

#pragma unroll
        for (int ks = 0; ks < 8; ++ks) {
            const int t = ct * 8 + ks;             // 0..127
            // ---- top: issue DMA(t+2) into buf[(t+2)%3]
            const int tp = (t + 2 < 128) ? t + 2 : 127;
            const int bw = (bcur == 0) ? 2 : bcur - 1;   // (bcur+2)%3
            char* nb = lds + (bw << 13) + (wid << 10);
            const size_t go = (size_t)(tp >> 3) * (FBN * DIM) + (size_t)(tp & 7) * 32 + goff;
            gload16(EThiH + go, nb);
            __builtin_amdgcn_sched_barrier(0);
            // ---- mid: consume buf[bcur]: 8 MFMA (xh*eh)
            const char* base = lds + (bcur << 13);
#pragma unroll
            for (int nf = 0; nf < 4; ++nf) {
                short8 bh = *(const short8*)(base + boff[nf]);
#pragma unroll
                for (int mf = 0; mf < 2; ++mf) {
                    acc[mf][nf] = __builtin_amdgcn_mfma_f32_16x16x32_bf16(ah[mf][ks], bh, acc[mf][nf], 0, 0, 0);
                }
            }
            __builtin_amdgcn_sched_barrier(0);
            // ---- end: wait DMA(t+1) only; DMA(t+2) stays in flight
            asm volatile("s_waitcnt vmcnt(1)" ::: "memory");
            __builtin_amdgcn_sched_barrier(0);
            __builtin_amdgcn_s_barrier();
            __builtin_amdgcn_sched_barrier(0);
            bcur = (bcur == 2) ? 0 : bcur + 1;
        }

        // ---- epilogue: d~ = emb_sqr - 2*M~; best + flag update
#pragma unroll
        for (int nf = 0; nf < 4; ++nf) {
            int col = chalf * 2048 + ct * FBN + wn * 64 + nf * 16 + l15;
            float esv = emb_sqr[col];
#pragma unroll
            for (int mf = 0; mf < 2; ++mf)
#pragma unroll
                for (int r = 0; r < 4; ++r) {
                    float da = __fmaf_rn(-2.f, acc[mf][nf][r], esv);
                    int s = mf * 4 + r;
                    if (da < v1r[s]) {
                        unsigned f = (v1r[s] - da < MARGIN) ? 0x80000000u : 0u;
                        v1r[s] = da; i1r[s] = (unsigned)col | f;
                    } else if (da - v1r[s] < MARGIN) {
                        i1r[s] |= 0x80000000u;
                    }
                }
        }
    }

    // ---- cross-entry reduce: per row 32 entries -> per-half partial to ws
    __syncthreads();   // full drain (incl. tail DMAs) before LDS reuse
    float*    v1s = (float*)lds;                       // [128][33] 16.9 KB
    unsigned* i1s = (unsigned*)(lds + 16896);          // [128][33] 16.9 KB
#pragma unroll
    for (int mf = 0; mf < 2; ++mf)
#pragma unroll
        for (int r = 0; r < 4; ++r) {
            int rl = wm * 32 + mf * 16 + l4 * 4 + r;
            int e = wn * 16 + l15;
            v1s[rl * 33 + e] = v1r[mf * 4 + r];
            i1s[rl * 33 + e] = i1r[mf * 4 + r];
        }
    __syncthreads();
    if (tid < FBM) {
        float bv = FLT_MAX; int bi = 0;
#pragma unroll
        for (int e = 0; e < 32; ++e) {
            float v = v1s[tid * 33 + e];
            int ix = (int)(i1s[tid * 33 + e] & 0x7FFFFFFFu);
            if (v < bv || (v == bv && ix < bi)) { bv = v; bi = ix; }
        }
        unsigned flag = 0u;
#pragma unroll
        for (int e = 0; e < 32; ++e) {
            float v = v1s[tid * 33 + e];
            unsigned ip = i1s[tid * 33 + e];
            if (v - bv < MARGIN) {
                if (ip & 0x80000000u) flag = 0x80000000u;             // intra-thread tie
                if ((int)(ip & 0x7FFFFFFFu) != bi) flag = 0x80000000u; // cross-thread tie
            }
        }
        size_t o = (size_t)chalf * N_ROWS + rowBase + tid;
        v1h[o] = bv;
        i1h[o] = (unsigned)bi | flag;
    }
}

// ===========================================================================
// k_merge: finalize per-row argmin over the two code halves; emit flags.
// Tie across halves -> half0 wins (its indices are lower). Cross-half
// near-tie (v_other - bv < MARGIN) => flag. Conservative-complete (see
// k_filter header proof).
// ===========================================================================
__launch_bounds__(256)
__global__ void k_merge(const float* __restrict__ v1h, const unsigned* __restrict__ i1h,
                        int* __restrict__ out_idx, int* __restrict__ flagcnt,
                        int* __restrict__ flaglist) {
    const int row = blockIdx.x * 256 + threadIdx.x;
    float v0 = v1h[row],          v1 = v1h[N_ROWS + row];
    unsigned p0 = i1h[row],       p1 = i1h[N_ROWS + row];
    float bv, vo; unsigned pb;
    if (v0 <= v1) { bv = v0; pb = p0; vo = v1; }   // tie -> half0 (lower idx)
    else          { bv = v1; pb = p1; vo = v0; }
    int bi = (int)(pb & 0x7FFFFFFFu);
    int flag = ((pb >> 31) != 0u) | (vo - bv < MARGIN);
    out_idx[row] = bi;
    if (flag) {
        int p = atomicAdd(flagcnt, 1);
        flaglist[p] = row;
    }
}

// ===========================================================================
// k_fixupw: np-bit-exact full rescan, 512 threads, batch 16 rows, 8 codes
// per thread (validated r12-r20: no spill at (512,2), lowest-index ties).
// ===========================================================================
__launch_bounds__(512, 2)
__global__ void k_fixupw(const float* __restrict__ X, const float* __restrict__ E,
                         const float* __restrict__ emb_sqr, const float* __restrict__ S,
                         const int* __restrict__ flagcnt, const int* __restrict__ flaglist,
                         int* __restrict__ out_idx) {
    __shared__ float xs[16][DIM];       // 16 KB
    __shared__ int rows[16];
    __shared__ float srow[16];
    __shared__ float rvw[8][16];        // [wave][row]
    __shared__ int   riw[8][16];
    const int tid = threadIdx.x;
    const int wv = tid >> 6;
    const int ln = tid & 63;
    const int cnt = *flagcnt;
    const int ngrp = (cnt + 15) >> 4;

    float es8[8];
#pragma unroll
    for (int j = 0; j < 8; ++j) es8[j] = emb_sqr[tid + 512 * j];

    for (int g = blockIdx.x; g < ngrp; g += gridDim.x) {
        if (tid < 16) {
            int fi = g * 16 + tid;
            if (fi >= cnt) fi = cnt - 1;
            int rw = flaglist[fi];
            rows[tid] = rw;
            srow[tid] = S[rw];
        }
        __syncthreads();
#pragma unroll
        for (int it = 0; it < 2; ++it) {
            int lin = it * 512 + tid;          // 0..1023 float4
            int r = lin >> 6, c4 = lin & 63;
            float4 v = *(const float4*)&X[(size_t)rows[r] * DIM + c4 * 4];
            xs[r][c4 * 4 + 0] = v.x; xs[r][c4 * 4 + 1] = v.y;
            xs[r][c4 * 4 + 2] = v.z; xs[r][c4 * 4 + 3] = v.w;
        }
        __syncthreads();

        float acc[16][8];
#pragma unroll
        for (int i = 0; i < 16; ++i)
#pragma unroll
            for (int j = 0; j < 8; ++j) acc[i][j] = 0.f;

        for (int d = 0; d < DIM; ++d) {
            const float* Ed = &E[(size_t)d * K_CODES + tid];
            float ev[8];
#pragma unroll
            for (int j = 0; j < 8; ++j) ev[j] = Ed[j * 512];
#pragma unroll
            for (int i = 0; i < 16; ++i) {
                float xv = xs[i][d];
#pragma unroll
                for (int j = 0; j < 8; ++j)
                    acc[i][j] = __fmaf_rn(xv, ev[j], acc[i][j]);
            }
        }

#pragma unroll
        for (int i = 0; i < 16; ++i) {
            const float Sr = srow[i];
            float bv = FLT_MAX;
            int bk = 0;
#pragma unroll
            for (int j = 0; j < 8; ++j) {      // ascending k within thread
                int k = tid + 512 * j;
                float dist = __fadd_rn(__fsub_rn(Sr, __fmul_rn(2.f, acc[i][j])), es8[j]);
                if (dist < bv) { bv = dist; bk = k; }
            }
            // wave lex-min (value, lowest index)
#pragma unroll
            for (int off = 32; off > 0; off >>= 1) {
                float vo = __shfl_xor(bv, off);
                int ko = __shfl_xor(bk, off);
                if (vo < bv || (vo == bv && ko < bk)) { bv = vo; bk = ko; }
            }
            if (ln == 0) { rvw[wv][i] = bv; riw[wv][i] = bk; }
        }
        __syncthreads();
        if (tid < 16) {
            float bv = rvw[0][tid];
            int bk = riw[0][tid];
#pragma unroll
            for (int w = 1; w < 8; ++w) {
                float v = rvw[w][tid];
                int k2 = riw[w][tid];
                if (v < bv || (v == bv && k2 < bk)) { bv = v; bk = k2; }
            }
            out_idx[rows[tid]] = bk;
        }
        __syncthreads();
    }
}

// ===========================================================================
// Fallback fp32 argmin (round-4, validated) for small-ws case
// ===========================================================================
#define BM 64
#define BN 256
#define DCHUNK 8
#define XS_LD 260

#define FMA8(a, b1, b2, accrow)                                       \
    do {                                                              \
        accrow[0] = __fmaf_rn((a), (b1).x, accrow[0]);                \
        accrow[1] = __fmaf_rn((a), (b1).y, accrow[1]);                \
        accrow[2] = __fmaf_rn((a), (b1).z, accrow[2]);                \
        accrow[3] = __fmaf_rn((a), (b1).w, accrow[3]);                \
        accrow[4] = __fmaf_rn((a), (b2).x, accrow[4]);                \
        accrow[5] = __fmaf_rn((a), (b2).y, accrow[5]);                \
        accrow[6] = __fmaf_rn((a), (b2).z, accrow[6]);                \
        accrow[7] = __fmaf_rn((a), (b2).w, accrow[7]);                \
    } while (0)

__launch_bounds__(256, 2)
__global__ void k_argmin(const float* __restrict__ X, const float* __restrict__ E,
                         const float* __restrict__ emb_sqr, const float* __restrict__ S,
                         int* __restrict__ out_idx) {
    __shared__ float Xs[BM][XS_LD];
    __shared__ float Es[DCHUNK][BN];
    const int tid = threadIdx.x;
    const int tx = tid & 31;
    const int ty = tid >> 5;
    const int rowBase = blockIdx.x * BM;
    const int r0 = ty * 8;
    {
        const float4* Xv = (const float4*)(X + (size_t)rowBase * DIM);
#pragma unroll
        for (int it = 0; it < 16; ++it) {
            int lin = it * 256 + tid;
            int r = lin >> 6, c4 = lin & 63;
            float4 v = Xv[lin];
            *(float4*)&Xs[r][c4 * 4] = v;
        }
    }
    float Srow[8];
#pragma unroll
    for (int i = 0; i < 8; ++i) Srow[i] = S[rowBase + r0 + i];
    float best[8];
    int bidx[8];
#pragma unroll
    for (int i = 0; i < 8; ++i) { best[i] = FLT_MAX; bidx[i] = 0; }
    for (int ct = 0; ct < K_CODES / BN; ++ct) {
        const int cbase = ct * BN;
        float acc[8][8];
#pragma unroll
        for (int i = 0; i < 8; ++i)
#pragma unroll
            for (int j = 0; j < 8; ++j) acc[i][j] = 0.f;
        for (int dc = 0; dc < DIM / DCHUNK; ++dc) {
            __syncthreads();
#pragma unroll
            for (int it = 0; it < 2; ++it) {
                int lin = it * 256 + tid;
                int r = lin >> 6, c4 = lin & 63;
                float4 v = *(const float4*)&E[(size_t)(dc * DCHUNK + r) * K_CODES + cbase + c4 * 4];
                *(float4*)&Es[r][c4 * 4] = v;
            }
            __syncthreads();
            const int db = dc * DCHUNK;
#pragma unroll
            for (int kk = 0; kk < DCHUNK; kk += 4) {
                float4 a4[8];
#pragma unroll
                for (int i = 0; i < 8; ++i)
                    a4[i] = *(const float4*)&Xs[r0 + i][db + kk];
                float4 bA[4], bB[4];
#pragma unroll
                for (int t = 0; t < 4; ++t) {
                    bA[t] = *(const float4*)&Es[kk + t][tx * 4];
                    bB[t] = *(const float4*)&Es[kk + t][128 + tx * 4];
                }
#pragma unroll
                for (int i = 0; i < 8; ++i) {
                    float4 av = a4[i];
                    FMA8(av.x, bA[0], bB[0], acc[i]);
                    FMA8(av.y, bA[1], bB[1], acc[i]);
                    FMA8(av.z, bA[2], bB[2], acc[i]);
                    FMA8(av.w, bA[3], bB[3], acc[i]);
                }
            }
        }
        float es[8];
#pragma unroll
        for (int j = 0; j < 4; ++j) es[j]     = emb_sqr[cbase + tx * 4 + j];
#pragma unroll
        for (int j = 0; j < 4; ++j) es[4 + j] = emb_sqr[cbase + 128 + tx * 4 + j];
#pragma unroll
        for (int i = 0; i < 8; ++i) {
#pragma unroll
            for (int j = 0; j < 8; ++j) {
                float d = __fadd_rn(__fsub_rn(Srow[i], __fmul_rn(2.f, acc[i][j])), es[j]);
                int cidx = cbase + ((j < 4) ? (tx * 4 + j) : (128 + tx * 4 + (j - 4)));
                if (d < best[i]) { best[i] = d; bidx[i] = cidx; }
            }
        }
    }
    __syncthreads();
    float* rv1 = &Xs[0][0];
    int*   ri1 = (int*)(rv1 + 2048);
#pragma unroll
    for (int i = 0; i < 8; ++i) {
        rv1[(r0 + i) * 32 + tx] = best[i];
        ri1[(r0 + i) * 32 + tx] = bidx[i];
    }
    __syncthreads();
    if (tid < BM) {
        float bv = rv1[tid * 32];
        int bi = ri1[tid * 32];
#pragma unroll
        for (int t = 1; t < 32; ++t) {
            float v = rv1[tid * 32 + t];
            int ix = ri1[tid * 32 + t];
            if (v < bv || (v == bv && ix < bi)) { bv = v; bi = ix; }
        }
        out_idx[rowBase + tid] = bi;
    }
}

// ===========================================================================
// Gather + loss
// ===========================================================================
__global__ void k_gather_et(const float* __restrict__ X, const float* __restrict__ ET,
                            const int* __restrict__ idx, float* __restrict__ out,
                            float* __restrict__ partials) {
    const int tid = threadIdx.x;
    const int total4 = N_ROWS * DIM / 4;
    float lsum = 0.f;
    for (int g = blockIdx.x * 256 + tid; g < total4; g += 2048 * 256) {
        int row = g >> 6;
        int d4 = g & 63;
        int k = idx[row];
        float4 z = *(const float4*)&X[(size_t)g * 4];
        float4 q = *(const float4*)&ET[(size_t)k * DIM + d4 * 4];
        float dx = __fsub_rn(q.x, z.x), dy = __fsub_rn(q.y, z.y);
        float dz = __fsub_rn(q.z, z.z), dw = __fsub_rn(q.w, z.w);
        float4 o;
        o.x = __fadd_rn(z.x, dx); o.y = __fadd_rn(z.y, dy);
        o.z = __fadd_rn(z.z, dz); o.w = __fadd_rn(z.w, dw);
        *(float4*)&out[(size_t)g * 4] = o;
        lsum += dx * dx + dy * dy + dz * dz + dw * dw;
    }
    __shared__ float red[256];
    red[tid] = lsum;
    __syncthreads();
    for (int s = 128; s > 0; s >>= 1) {
        if (tid < s) red[tid] += red[tid + s];
        __syncthreads();
    }
    if (tid == 0) partials[blockIdx.x] = red[0];
}

__global__ void k_gather_e(const float* __restrict__ X, const float* __restrict__ E,
                           const int* __restrict__ idx, float* __restrict__ out,
                           float* __restrict__ partials) {
    const int tid = threadIdx.x;
    const int total4 = N_ROWS * DIM / 4;
    float lsum = 0.f;
    for (int g = blockIdx.x * 256 + tid; g < total4; g += 2048 * 256) {
        int row = g >> 6;
        int d4 = g & 63;
        int k = idx[row];
        float4 z = *(const float4*)&X[(size_t)g * 4];
        float4 q;
        q.x = E[(size_t)(d4 * 4 + 0) * K_CODES + k];
        q.y = E[(size_t)(d4 * 4 + 1) * K_CODES + k];
        q.z = E[(size_t)(d4 * 4 + 2) * K_CODES + k];
        q.w = E[(size_t)(d4 * 4 + 3) * K_CODES + k];
        float dx = __fsub_rn(q.x, z.x), dy = __fsub_rn(q.y, z.y);
        float dz = __fsub_rn(q.z, z.z), dw = __fsub_rn(q.w, z.w);
        float4 o;
        o.x = __fadd_rn(z.x, dx); o.y = __fadd_rn(z.y, dy);
        o.z = __fadd_rn(z.z, dz); o.w = __fadd_rn(z.w, dw);
        *(float4*)&out[(size_t)g * 4] = o;
        lsum += dx * dx + dy * dy + dz * dz + dw * dw;
    }
    __shared__ float red[256];
    red[tid] = lsum;
    __syncthreads();
    for (int s = 128; s > 0; s >>= 1) {
        if (tid < s) red[tid] += red[tid + s];
        __syncthreads();
    }
    if (tid == 0) partials[blockIdx.x] = red[0];
}

__global__ void k_loss(const float* __restrict__ partials, float* __restrict__ out_loss) {
    __shared__ float red[256];
    const int tid = threadIdx.x;
    float s = 0.f;
    for (int i = tid; i < 2048; i += 256) s += partials[i];
    red[tid] = s;
    __syncthreads();
    for (int st = 128; st > 0; st >>= 1) {
        if (tid < st) red[tid] += red[tid + st];
        __syncthreads();
    }
    if (tid == 0) out_loss[0] = 1.25f * red[0] / 16777216.0f;
}

// ===========================================================================
extern "C" void kernel_launch(void* const* d_in, const int* in_sizes, int n_in,
                              void* d_out, int out_size, void* d_ws, size_t ws_size,
                              hipStream_t stream) {
    (void)in_sizes; (void)n_in; (void)out_size;
    const float* X = (const float*)d_in[0];   // z_latents [65536][256]
    const float* E = (const float*)d_in[1];   // embeddings [256][4096]
    float* out = (float*)d_out;

    char* ws = (char*)d_ws;
    int*   idx      = (int*)ws;                         // @0        256 KB
    float* emb_sqr  = (float*)(ws + 262144);            // @262144   16 KB
    float* S        = (float*)(ws + 278528);            // @278528   256 KB
    float* partials = (float*)(ws + 540672);            // @540672   8 KB
    int*   flagcnt  = (int*)(ws + 548864);              // @548864   256 B
    int*   flaglist = (int*)(ws + 549120);              // @549120   256 KB
    float* ET       = (float*)(ws + 811264);            // @811264   4 MB
    unsigned short* EThi = (unsigned short*)(ws + 5005568);  // 2 MB
    float*    v1h  = (float*)(ws + 7102720);            // 512 KB (2 x 65536 f32)
    unsigned* i1h  = (unsigned*)(ws + 7626752);         // 512 KB
    const size_t WS_NEED = 8150784;

    if (ws_size >= WS_NEED) {
        k_prep<<<2064, 256, 0, stream>>>(X, E, emb_sqr, S, ET, EThi, flagcnt);
        k_filter<<<dim3(N_ROWS / FBM, 2), 512, 0, stream>>>(X, EThi, emb_sqr, v1h, i1h);
        k_merge<<<N_ROWS / 256, 256, 0, stream>>>(v1h, i1h, idx, flagcnt, flaglist);
        k_fixupw<<<1024, 512, 0, stream>>>(X, E, emb_sqr, S, flagcnt, flaglist, idx);
        k_gather_et<<<2048, 256, 0, stream>>>(X, ET, idx, out, partials);
    } else {
        k_prep<<<1040, 256, 0, stream>>>(X, E, emb_sqr, S, ET, EThi, flagcnt);  // emb_sqr+S only
        k_argmin<<<N_ROWS / BM, 256, 0, stream>>>(X, E, emb_sqr, S, idx);
        k_gather_e<<<2048, 256, 0, stream>>>(X, E, idx, out, partials);
    }
    k_loss<<<1, 256, 0, stream>>>(partials, out + (size_t)N_ROWS * DIM);
}

// Round 22
// 429.484 us; speedup vs baseline: 1.0418x; 1.0418x over previous
//
#include <hip/hip_runtime.h>
#include <float.h>

#define N_ROWS 65536
#define DIM 256
#define K_CODES 4096
#define MARGIN 0.025f

typedef __attribute__((ext_vector_type(8))) short short8;   // 8 bf16 (4 VGPR)
typedef __attribute__((ext_vector_type(4))) float f32x4;
typedef __attribute__((ext_vector_type(4))) unsigned int u32x4;

__device__ __forceinline__ unsigned short f2bf(float f) {   // RNE
    unsigned u = __float_as_uint(f);
    return (unsigned short)((u + 0x7FFFu + ((u >> 16) & 1u)) >> 16);
}
__device__ __forceinline__ float bf2f(unsigned short h) {
    return __uint_as_float((unsigned)h << 16);
}

// async global->LDS DMA, 16B per lane; LDS dest = wave-uniform base + lane*16
__device__ __forceinline__ void gload16(const void* gsrc, void* ldst) {
    __builtin_amdgcn_global_load_lds(
        (__attribute__((address_space(1))) unsigned int*)gsrc,
        (__attribute__((address_space(3))) unsigned int*)ldst,
        16, 0, 0);
}

// ===========================================================================
// k_prep: fused prep (validated r20). blockIdx ranges:
//   [0,16) emb_sqr (+flagcnt=0) | [16,1040) inp_sqr | [1040,2064) esplit
// ===========================================================================
__launch_bounds__(256)
__global__ void k_prep(const float* __restrict__ X, const float* __restrict__ E,
                       float* __restrict__ emb_sqr, float* __restrict__ S,
                       float* __restrict__ ET, unsigned short* __restrict__ EThi,
                       int* __restrict__ flagcnt) {
    const int bid = blockIdx.x;
    const int tid = threadIdx.x;

    if (bid < 16) {
        if (bid == 0 && tid == 0) *flagcnt = 0;
        int k = bid * 256 + tid;
        float e0 = E[k];
        float s = __fmul_rn(e0, e0);
        for (int d = 1; d < DIM; ++d) {
            float v = E[(size_t)d * K_CODES + k];
            s = __fadd_rn(s, __fmul_rn(v, v));
        }
        emb_sqr[k] = s;
    } else if (bid < 1040) {
        __shared__ float xs[64][261];
        const int rowBase = (bid - 16) * 64;
        const float4* Xv = (const float4*)(X + (size_t)rowBase * DIM);
#pragma unroll
        for (int it = 0; it < 16; ++it) {
            int lin = it * 256 + tid;
            int r = lin >> 6, c4 = lin & 63;
            float4 v = Xv[lin];
            xs[r][c4 * 4 + 0] = v.x; xs[r][c4 * 4 + 1] = v.y;
            xs[r][c4 * 4 + 2] = v.z; xs[r][c4 * 4 + 3] = v.w;
        }
        __syncthreads();
        if (tid < 64) {
            const float* x = xs[tid];
            float b[2];
#pragma unroll
            for (int h = 0; h < 2; ++h) {
                const float* p = x + h * 128;
                float r[8];
#pragma unroll
                for (int j = 0; j < 8; ++j) r[j] = __fmul_rn(p[j], p[j]);
                for (int i = 8; i < 128; i += 8)
#pragma unroll
                    for (int j = 0; j < 8; ++j)
                        r[j] = __fadd_rn(r[j], __fmul_rn(p[i + j], p[i + j]));
                b[h] = __fadd_rn(__fadd_rn(__fadd_rn(r[0], r[1]), __fadd_rn(r[2], r[3])),
                                 __fadd_rn(__fadd_rn(r[4], r[5]), __fadd_rn(r[6], r[7])));
            }
            S[rowBase + tid] = __fadd_rn(b[0], b[1]);
        }
    } else {
        __shared__ float t[32][33];
        const int e = bid - 1040;               // 0..1023
        const int k0 = (e & 127) * 32;
        const int d0 = (e >> 7) * 32;
        const int tx = tid & 31, ty = tid >> 5;
#pragma unroll
        for (int i = 0; i < 32; i += 8)
            t[ty + i][tx] = E[(size_t)(d0 + ty + i) * K_CODES + k0 + tx];
        __syncthreads();
#pragma unroll
        for (int i = 0; i < 32; i += 8) {
            float w = t[tx][ty + i];
            size_t o = (size_t)(k0 + ty + i) * DIM + d0 + tx;
            ET[o] = w;
            EThi[o] = f2bf(w);
        }
    }
}

// ===========================================================================
// k_filter: r18/r20 configuration VERBATIM (measured best: 291 us filter /
// 431 us total). 1-TERM (M~ = xh*eh), flag-bit top-tie tracking, triple-
// buffered B via gload_lds, counted vmcnt(1), r8 swizzle pair, fences.
// 128 rows x 128 codes, 8 waves. Conservative-correct at M=0.025;
// absmax 0 in r10/r11/r18/r20. Plateau established over r13-r21.
// ===========================================================================
#define FBM 128
#define FBN 128

__launch_bounds__(512, 4)
__global__ void k_filter(const float* __restrict__ X,
                         const unsigned short* __restrict__ EThi,
                         const float* __restrict__ emb_sqr,
                         int* __restrict__ out_idx, int* __restrict__ flagcnt,
                         int* __restrict__ flaglist) {
    __shared__ __align__(16) char lds[33792];   // bufs 3x8KB; reduce aliases

    const int tid = threadIdx.x;
    const int lane = tid & 63;
    const int wid = tid >> 6;
    const int wm = wid & 3;          // row-wave: 32 rows each
    const int wn = wid >> 2;         // col-wave: 64 codes each
    const int rowBase = blockIdx.x * FBM;
    const int l15 = lane & 15, l4 = lane >> 4;

    // ---- prologue: stage Xh slice per 32-d step, load A-frags to registers
    short8 ah[2][8];
    {
        const int prow = tid >> 2;              // 0..127
        const int pd = (tid & 3) * 8;           // 0,8,16,24
        const int wroff = prow * 128 + ((pd * 2) ^ ((prow & 7) << 4));
#pragma unroll
        for (int ks = 0; ks < 8; ++ks) {
            float4 v0 = *(const float4*)&X[(size_t)(rowBase + prow) * DIM + ks * 32 + pd];
            float4 v1 = *(const float4*)&X[(size_t)(rowBase + prow) * DIM + ks * 32 + pd + 4];
            float f[8] = {v0.x, v0.y, v0.z, v0.w, v1.x, v1.y, v1.z, v1.w};
            unsigned H[4];
#pragma unroll
            for (int p = 0; p < 4; ++p) {
                unsigned short ha = f2bf(f[2 * p]), hb = f2bf(f[2 * p + 1]);
                H[p] = (unsigned)ha | ((unsigned)hb << 16);
            }
            u32x4 Hv = {H[0], H[1], H[2], H[3]};
            *(u32x4*)(lds + wroff) = Hv;
            __syncthreads();
#pragma unroll
            for (int mf = 0; mf < 2; ++mf) {
                int rl = wm * 32 + mf * 16 + l15;
                int off = rl * 128 + ((l4 * 16) ^ ((rl & 7) << 4));
                ah[mf][ks] = *(const short8*)(lds + off);
            }
            __syncthreads();   // full drain -> clean counter slate
        }
    }

    // ---- per-(mf,r) best + packed(idx | flag<<31)
    float v1r[8];
    unsigned i1r[8];
#pragma unroll
    for (int s = 0; s < 8; ++s) { v1r[s] = FLT_MAX; i1r[s] = 0u; }

    // ---- gload_lds source geometry (rule #21 inverse swizzle, validated r8)
    const int gr = (wid << 4) + (lane >> 2);
    const int gc = (lane & 3) ^ ((lane >> 3) & 3);
    const size_t goff = (size_t)gr * DIM + gc * 8;      // u16 elements

    // ---- B-frag read offsets (swizzled), hoisted
    int boff[4];
#pragma unroll
    for (int nf = 0; nf < 4; ++nf) {
        int cl = wn * 64 + nf * 16 + l15;
        boff[nf] = cl * 64 + ((l4 ^ ((cl >> 1) & 3)) << 4);
    }

    // ---- stage slices 0 (buf0) and 1 (buf1)
    gload16(EThi + goff, lds + (wid << 10));
    gload16(EThi + 32 + goff, lds + 8192 + (wid << 10));
    asm volatile("s_waitcnt vmcnt(1)" ::: "memory");   // slice 0 landed
    __builtin_amdgcn_sched_barrier(0);
    __builtin_amdgcn_s_barrier();
    __builtin_amdgcn_sched_barrier(0);

    int bcur = 0;   // buffer holding slice t; rotates 0->1->2->0
    for (int ct = 0; ct < K_CODES / FBN; ++ct) {   // 32 code tiles
        f32x4 acc[2][4];
#pragma unroll
        for (int mf = 0; mf < 2; ++mf)
#pragma unroll
            for (int nf = 0; nf < 4; ++nf) acc[mf][nf] = (f32x4)0.f;

#pragma unroll
        for (int ks = 0; ks < 8; ++ks) {
            const int t = ct * 8 + ks;
            // ---- top: issue DMA(t+2) into buf[(t+2)%3]
            const int tp = (t + 2 < 256) ? t + 2 : 255;
            const int bw = (bcur == 0) ? 2 : bcur - 1;   // (bcur+2)%3
            char* nb = lds + (bw << 13) + (wid << 10);
            const size_t go = (size_t)(tp >> 3) * (FBN * DIM) + (size_t)(tp & 7) * 32 + goff;
            gload16(EThi + go, nb);
            __builtin_amdgcn_sched_barrier(0);
            // ---- mid: consume buf[bcur]: 8 MFMA (xh*eh)
            const char* base = lds + (bcur << 13);
#pragma unroll
            for (int nf = 0; nf < 4; ++nf) {
                short8 bh = *(const short8*)(base + boff[nf]);
#pragma unroll
                for (int mf = 0; mf < 2; ++mf) {
                    acc[mf][nf] = __builtin_amdgcn_mfma_f32_16x16x32_bf16(ah[mf][ks], bh, acc[mf][nf], 0, 0, 0);
                }
            }
            __builtin_amdgcn_sched_barrier(0);
            // ---- end: wait DMA(t+1) only; DMA(t+2) stays in flight
            asm volatile("s_waitcnt vmcnt(1)" ::: "memory");
            __builtin_amdgcn_sched_barrier(0);
            __builtin_amdgcn_s_barrier();
            __builtin_amdgcn_sched_barrier(0);
            bcur = (bcur == 2) ? 0 : bcur + 1;
        }

        // ---- epilogue: d~ = emb_sqr - 2*M~; best + flag update
#pragma unroll
        for (int nf = 0; nf < 4; ++nf) {
            int col = ct * FBN + wn * 64 + nf * 16 + l15;
            float esv = emb_sqr[col];
#pragma unroll
            for (int mf = 0; mf < 2; ++mf)
#pragma unroll
                for (int r = 0; r < 4; ++r) {
                    float da = __fmaf_rn(-2.f, acc[mf][nf][r], esv);
                    int s = mf * 4 + r;
                    if (da < v1r[s]) {
                        unsigned f = (v1r[s] - da < MARGIN) ? 0x80000000u : 0u;
                        v1r[s] = da; i1r[s] = (unsigned)col | f;
                    } else if (da - v1r[s] < MARGIN) {
                        i1r[s] |= 0x80000000u;
                    }
                }
        }
    }

    // ---- cross-entry reduce: per row 32 entries (2 col-waves x 16 lanes)
    __syncthreads();   // full drain (incl. tail DMAs) before LDS reuse
    float*    v1s = (float*)lds;                       // [128][33] 16.9 KB
    unsigned* i1s = (unsigned*)(lds + 16896);          // [128][33] 16.9 KB
#pragma unroll
    for (int mf = 0; mf < 2; ++mf)
#pragma unroll
        for (int r = 0; r < 4; ++r) {
            int rl = wm * 32 + mf * 16 + l4 * 4 + r;
            int e = wn * 16 + l15;
            v1s[rl * 33 + e] = v1r[mf * 4 + r];
            i1s[rl * 33 + e] = i1r[mf * 4 + r];
        }
    __syncthreads();
    if (tid < FBM) {
        float bv = FLT_MAX; int bi = 0;
#pragma unroll
        for (int e = 0; e < 32; ++e) {
            float v = v1s[tid * 33 + e];
            int ix = (int)(i1s[tid * 33 + e] & 0x7FFFFFFFu);
            if (v < bv || (v == bv && ix < bi)) { bv = v; bi = ix; }
        }
        int flag = 0;
#pragma unroll
        for (int e = 0; e < 32; ++e) {
            float v = v1s[tid * 33 + e];
            unsigned ip = i1s[tid * 33 + e];
            if (v - bv < MARGIN) {
                if (ip & 0x80000000u) flag = 1;                       // intra-thread tie
                if ((int)(ip & 0x7FFFFFFFu) != bi) flag = 1;          // cross-thread tie
            }
        }
        out_idx[rowBase + tid] = bi;
        if (flag) {
            int p = atomicAdd(flagcnt, 1);
            flaglist[p] = rowBase + tid;
        }
    }
}

// ===========================================================================
// k_fixupw: np-bit-exact full rescan, 512 threads, batch 16 rows, 8 codes
// per thread (validated r12-r20: no spill at (512,2), lowest-index ties).
// ===========================================================================
__launch_bounds__(512, 2)
__global__ void k_fixupw(const float* __restrict__ X, const float* __restrict__ E,
                         const float* __restrict__ emb_sqr, const float* __restrict__ S,
                         const int* __restrict__ flagcnt, const int* __restrict__ flaglist,
                         int* __restrict__ out_idx) {
    __shared__ float xs[16][DIM];       // 16 KB
    __shared__ int rows[16];
    __shared__ float srow[16];
    __shared__ float rvw[8][16];        // [wave][row]
    __shared__ int   riw[8][16];
    const int tid = threadIdx.x;
    const int wv = tid >> 6;
    const int ln = tid & 63;
    const int cnt = *flagcnt;
    const int ngrp = (cnt + 15) >> 4;

    float es8[8];
#pragma unroll
    for (int j = 0; j < 8; ++j) es8[j] = emb_sqr[tid + 512 * j];

    for (int g = blockIdx.x; g < ngrp; g += gridDim.x) {
        if (tid < 16) {
            int fi = g * 16 + tid;
            if (fi >= cnt) fi = cnt - 1;
            int rw = flaglist[fi];
            rows[tid] = rw;
            srow[tid] = S[rw];
        }
        __syncthreads();
#pragma unroll
        for (int it = 0; it < 2; ++it) {
            int lin = it * 512 + tid;          // 0..1023 float4
            int r = lin >> 6, c4 = lin & 63;
            float4 v = *(const float4*)&X[(size_t)rows[r] * DIM + c4 * 4];
            xs[r][c4 * 4 + 0] = v.x; xs[r][c4 * 4 + 1] = v.y;
            xs[r][c4 * 4 + 2] = v.z; xs[r][c4 * 4 + 3] = v.w;
        }
        __syncthreads();

        float acc[16][8];
#pragma unroll
        for (int i = 0; i < 16; ++i)
#pragma unroll
            for (int j = 0; j < 8; ++j) acc[i][j] = 0.f;

        for (int d = 0; d < DIM; ++d) {
            const float* Ed = &E[(size_t)d * K_CODES + tid];
            float ev[8];
#pragma unroll
            for (int j = 0; j < 8; ++j) ev[j] = Ed[j * 512];
#pragma unroll
            for (int i = 0; i < 16; ++i) {
                float xv = xs[i][d];
#pragma unroll
                for (int j = 0; j < 8; ++j)
                    acc[i][j] = __fmaf_rn(xv, ev[j], acc[i][j]);
            }
        }

#pragma unroll
        for (int i = 0; i < 16; ++i) {
            const float Sr = srow[i];
            float bv = FLT_MAX;
            int bk = 0;
#pragma unroll
            for (int j = 0; j < 8; ++j) {      // ascending k within thread
                int k = tid + 512 * j;
                float dist = __fadd_rn(__fsub_rn(Sr, __fmul_rn(2.f, acc[i][j])), es8[j]);
                if (dist < bv) { bv = dist; bk = k; }
            }
            // wave lex-min (value, lowest index)
#pragma unroll
            for (int off = 32; off > 0; off >>= 1) {
                float vo = __shfl_xor(bv, off);
                int ko = __shfl_xor(bk, off);
                if (vo < bv || (vo == bv && ko < bk)) { bv = vo; bk = ko; }
            }
            if (ln == 0) { rvw[wv][i] = bv; riw[wv][i] = bk; }
        }
        __syncthreads();
        if (tid < 16) {
            float bv = rvw[0][tid];
            int bk = riw[0][tid];
#pragma unroll
            for (int w = 1; w < 8; ++w) {
                float v = rvw[w][tid];
                int k2 = riw[w][tid];
                if (v < bv || (v == bv && k2 < bk)) { bv = v; bk = k2; }
            }
            out_idx[rows[tid]] = bk;
        }
        __syncthreads();
    }
}

// ===========================================================================
// Fallback fp32 argmin (round-4, validated) for small-ws case
// ===========================================================================
#define BM 64
#define BN 256
#define DCHUNK 8
#define XS_LD 260

#define FMA8(a, b1, b2, accrow)                                       \
    do {                                                              \
        accrow[0] = __fmaf_rn((a), (b1).x, accrow[0]);                \
        accrow[1] = __fmaf_rn((a), (b1).y, accrow[1]);                \
        accrow[2] = __fmaf_rn((a), (b1).z, accrow[2]);                \
        accrow[3] = __fmaf_rn((a), (b1).w, accrow[3]);                \
        accrow[4] = __fmaf_rn((a), (b2).x, accrow[4]);                \
        accrow[5] = __fmaf_rn((a), (b2).y, accrow[5]);                \
        accrow[6] = __fmaf_rn((a), (b2).z, accrow[6]);                \
        accrow[7] = __fmaf_rn((a), (b2).w, accrow[7]);                \
    } while (0)

__launch_bounds__(256, 2)
__global__ void k_argmin(const float* __restrict__ X, const float* __restrict__ E,
                         const float* __restrict__ emb_sqr, const float* __restrict__ S,
                         int* __restrict__ out_idx) {
    __shared__ float Xs[BM][XS_LD];
    __shared__ float Es[DCHUNK][BN];
    const int tid = threadIdx.x;
    const int tx = tid & 31;
    const int ty = tid >> 5;
    const int rowBase = blockIdx.x * BM;
    const int r0 = ty * 8;
    {
        const float4* Xv = (const float4*)(X + (size_t)rowBase * DIM);
#pragma unroll
        for (int it = 0; it < 16; ++it) {
            int lin = it * 256 + tid;
            int r = lin >> 6, c4 = lin & 63;
            float4 v = Xv[lin];
            *(float4*)&Xs[r][c4 * 4] = v;
        }
    }
    float Srow[8];
#pragma unroll
    for (int i = 0; i < 8; ++i) Srow[i] = S[rowBase + r0 + i];
    float best[8];
    int bidx[8];
#pragma unroll
    for (int i = 0; i < 8; ++i) { best[i] = FLT_MAX; bidx[i] = 0; }
    for (int ct = 0; ct < K_CODES / BN; ++ct) {
        const int cbase = ct * BN;
        float acc[8][8];
#pragma unroll
        for (int i = 0; i < 8; ++i)
#pragma unroll
            for (int j = 0; j < 8; ++j) acc[i][j] = 0.f;
        for (int dc = 0; dc < DIM / DCHUNK; ++dc) {
            __syncthreads();
#pragma unroll
            for (int it = 0; it < 2; ++it) {
                int lin = it * 256 + tid;
                int r = lin >> 6, c4 = lin & 63;
                float4 v = *(const float4*)&E[(size_t)(dc * DCHUNK + r) * K_CODES + cbase + c4 * 4];
                *(float4*)&Es[r][c4 * 4] = v;
            }
            __syncthreads();
            const int db = dc * DCHUNK;
#pragma unroll
            for (int kk = 0; kk < DCHUNK; kk += 4) {
                float4 a4[8];
#pragma unroll
                for (int i = 0; i < 8; ++i)
                    a4[i] = *(const float4*)&Xs[r0 + i][db + kk];
                float4 bA[4], bB[4];
#pragma unroll
                for (int t = 0; t < 4; ++t) {
                    bA[t] = *(const float4*)&Es[kk + t][tx * 4];
                    bB[t] = *(const float4*)&Es[kk + t][128 + tx * 4];
                }
#pragma unroll
                for (int i = 0; i < 8; ++i) {
                    float4 av = a4[i];
                    FMA8(av.x, bA[0], bB[0], acc[i]);
                    FMA8(av.y, bA[1], bB[1], acc[i]);
                    FMA8(av.z, bA[2], bB[2], acc[i]);
                    FMA8(av.w, bA[3], bB[3], acc[i]);
                }
            }
        }
        float es[8];
#pragma unroll
        for (int j = 0; j < 4; ++j) es[j]     = emb_sqr[cbase + tx * 4 + j];
#pragma unroll
        for (int j = 0; j < 4; ++j) es[4 + j] = emb_sqr[cbase + 128 + tx * 4 + j];
#pragma unroll
        for (int i = 0; i < 8; ++i) {
#pragma unroll
            for (int j = 0; j < 8; ++j) {
                float d = __fadd_rn(__fsub_rn(Srow[i], __fmul_rn(2.f, acc[i][j])), es[j]);
                int cidx = cbase + ((j < 4) ? (tx * 4 + j) : (128 + tx * 4 + (j - 4)));
                if (d < best[i]) { best[i] = d; bidx[i] = cidx; }
            }
        }
    }
    __syncthreads();
    float* rv1 = &Xs[0][0];
    int*   ri1 = (int*)(rv1 + 2048);
#pragma unroll
    for (int i = 0; i < 8; ++i) {
        rv1[(r0 + i) * 32 + tx] = best[i];
        ri1[(r0 + i) * 32 + tx] = bidx[i];
    }
    __syncthreads();
    if (tid < BM) {
        float bv = rv1[tid * 32];
        int bi = ri1[tid * 32];
#pragma unroll
        for (int t = 1; t < 32; ++t) {
            float v = rv1[tid * 32 + t];
            int ix = ri1[tid * 32 + t];
            if (v < bv || (v == bv && ix < bi)) { bv = v; bi = ix; }
        }
        out_idx[rowBase + tid] = bi;
    }
}

// ===========================================================================
// Gather + loss
// ===========================================================================
__global__ void k_gather_et(const float* __restrict__ X, const float* __restrict__ ET,
                            const int* __restrict__ idx, float* __restrict__ out,
                            float* __restrict__ partials) {
    const int tid = threadIdx.x;
    const int total4 = N_ROWS * DIM / 4;
    float lsum = 0.f;
    for (int g = blockIdx.x * 256 + tid; g < total4; g += 2048 * 256) {
        int row = g >> 6;
        int d4 = g & 63;
        int k = idx[row];
        float4 z = *(const float4*)&X[(size_t)g * 4];
        float4 q = *(const float4*)&ET[(size_t)k * DIM + d4 * 4];
        float dx = __fsub_rn(q.x, z.x), dy = __fsub_rn(q.y, z.y);
        float dz = __fsub_rn(q.z, z.z), dw = __fsub_rn(q.w, z.w);
        float4 o;
        o.x = __fadd_rn(z.x, dx); o.y = __fadd_rn(z.y, dy);
        o.z = __fadd_rn(z.z, dz); o.w = __fadd_rn(z.w, dw);
        *(float4*)&out[(size_t)g * 4] = o;
        lsum += dx * dx + dy * dy + dz * dz + dw * dw;
    }
    __shared__ float red[256];
    red[tid] = lsum;
    __syncthreads();
    for (int s = 128; s > 0; s >>= 1) {
        if (tid < s) red[tid] += red[tid + s];
        __syncthreads();
    }
    if (tid == 0) partials[blockIdx.x] = red[0];
}

__global__ void k_gather_e(const float* __restrict__ X, const float* __restrict__ E,
                           const int* __restrict__ idx, float* __restrict__ out,
                           float* __restrict__ partials) {
    const int tid = threadIdx.x;
    const int total4 = N_ROWS * DIM / 4;
    float lsum = 0.f;
    for (int g = blockIdx.x * 256 + tid; g < total4; g += 2048 * 256) {
        int row = g >> 6;
        int d4 = g & 63;
        int k = idx[row];
        float4 z = *(const float4*)&X[(size_t)g * 4];
        float4 q;
        q.x = E[(size_t)(d4 * 4 + 0) * K_CODES + k];
        q.y = E[(size_t)(d4 * 4 + 1) * K_CODES + k];
        q.z = E[(size_t)(d4 * 4 + 2) * K_CODES + k];
        q.w = E[(size_t)(d4 * 4 + 3) * K_CODES + k];
        float dx = __fsub_rn(q.x, z.x), dy = __fsub_rn(q.y, z.y);
        float dz = __fsub_rn(q.z, z.z), dw = __fsub_rn(q.w, z.w);
        float4 o;
        o.x = __fadd_rn(z.x, dx); o.y = __fadd_rn(z.y, dy);
        o.z = __fadd_rn(z.z, dz); o.w = __fadd_rn(z.w, dw);
        *(float4*)&out[(size_t)g * 4] = o;
        lsum += dx * dx + dy * dy + dz * dz + dw * dw;
    }
    __shared__ float red[256];
    red[tid] = lsum;
    __syncthreads();
    for (int s = 128; s > 0; s >>= 1) {
        if (tid < s) red[tid] += red[tid + s];
        __syncthreads();
    }
    if (tid == 0) partials[blockIdx.x] = red[0];
}

__global__ void k_loss(const float* __restrict__ partials, float* __restrict__ out_loss) {
    __shared__ float red[256];
    const int tid = threadIdx.x;
    float s = 0.f;
    for (int i = tid; i < 2048; i += 256) s += partials[i];
    red[tid] = s;
    __syncthreads();
    for (int st = 128; st > 0; st >>= 1) {
        if (tid < st) red[tid] += red[tid + st];
        __syncthreads();
    }
    if (tid == 0) out_loss[0] = 1.25f * red[0] / 16777216.0f;
}

// ===========================================================================
extern "C" void kernel_launch(void* const* d_in, const int* in_sizes, int n_in,
                              void* d_out, int out_size, void* d_ws, size_t ws_size,
                              hipStream_t stream) {
    (void)in_sizes; (void)n_in; (void)out_size;
    const float* X = (const float*)d_in[0];   // z_latents [65536][256]
    const float* E = (const float*)d_in[1];   // embeddings [256][4096]
    float* out = (float*)d_out;

    char* ws = (char*)d_ws;
    int*   idx      = (int*)ws;                         // @0        256 KB
    float* emb_sqr  = (float*)(ws + 262144);            // @262144   16 KB
    float* S        = (float*)(ws + 278528);            // @278528   256 KB
    float* partials = (float*)(ws + 540672);            // @540672   8 KB
    int*   flagcnt  = (int*)(ws + 548864);              // @548864   256 B
    int*   flaglist = (int*)(ws + 549120);              // @549120   256 KB
    float* ET       = (float*)(ws + 811264);            // @811264   4 MB
    unsigned short* EThi = (unsigned short*)(ws + 5005568);  // 2 MB
    const size_t WS_NEED = 7102720;

    if (ws_size >= WS_NEED) {
        k_prep<<<2064, 256, 0, stream>>>(X, E, emb_sqr, S, ET, EThi, flagcnt);
        k_filter<<<N_ROWS / FBM, 512, 0, stream>>>(X, EThi, emb_sqr, idx, flagcnt, flaglist);
        k_fixupw<<<1024, 512, 0, stream>>>(X, E, emb_sqr, S, flagcnt, flaglist, idx);
        k_gather_et<<<2048, 256, 0, stream>>>(X, ET, idx, out, partials);
    } else {
        k_prep<<<1040, 256, 0, stream>>>(X, E, emb_sqr, S, ET, EThi, flagcnt);  // emb_sqr+S only
        k_argmin<<<N_ROWS / BM, 256, 0, stream>>>(X, E, emb_sqr, S, idx);
        k_gather_e<<<2048, 256, 0, stream>>>(X, E, idx, out, partials);
    }
    k_loss<<<1, 256, 0, stream>>>(partials, out + (size_t)N_ROWS * DIM);
}